// Round 3
// baseline (50.889 us; speedup 1.0000x reference)
//
#include <hip/hip_runtime.h>
#include <math.h>

// SparseMixer MoE routing: T tokens x 128 experts, top-2.
// Per token t:
//   (v1,i1) = max/argmax(logits)
//   kept:  (v1 - x)/max(|x|, v1) <= 2*EPS   (NaN compare-false => kept, matches jnp)
//   val0 = 1 / sum_kept exp(x - v1)
//   set x[i1] = -inf; (v2,i2) = max/argmax; same formula -> val1
// Output (floats): out[0..2T)   = indices (as float, token-major, k inner)
//                  out[2T..4T)  = values
//
// 16 lanes per token; each lane owns 8 experts via two float4 loads.
// (Second resubmission: rounds 1 and 2 both died with UnresponsiveContainer
//  before any compile/run — no evidence yet about this kernel.)

#define TWO_EPS 0.02f
#define NEXPERTS 128

__global__ __launch_bounds__(256) void sparsemixer_route_kernel(
    const float* __restrict__ logits,
    float* __restrict__ out,
    int T)
{
    const int gtid  = blockIdx.x * blockDim.x + threadIdx.x;
    const int token = gtid >> 4;          // 16 lanes per token
    const int sub   = threadIdx.x & 15;   // lane within the 16-group
    if (token >= T) return;

    const float4* p = reinterpret_cast<const float4*>(logits + (size_t)token * NEXPERTS);
    float4 a = p[sub];        // experts [sub*4, sub*4+4)
    float4 b = p[sub + 16];   // experts [64 + sub*4, ...)

    float x[8] = {a.x, a.y, a.z, a.w, b.x, b.y, b.z, b.w};
    int   e[8];
    #pragma unroll
    for (int k = 0; k < 4; ++k) { e[k] = sub * 4 + k; e[k + 4] = 64 + sub * 4 + k; }

    float val_out[2];
    int   idx_out[2];

    #pragma unroll
    for (int pass = 0; pass < 2; ++pass) {
        // ---- max/argmax over this lane's 8 (indices scanned ascending => first-occurrence tie-break)
        float v = -INFINITY;
        int   idx = 0x7fffffff;
        #pragma unroll
        for (int k = 0; k < 8; ++k) {
            if (x[k] > v) { v = x[k]; idx = e[k]; }
        }
        // ---- 16-lane arg-reduce (xor masks 8,4,2,1 stay within the group)
        #pragma unroll
        for (int off = 8; off > 0; off >>= 1) {
            float ov = __shfl_xor(v, off);
            int   oi = __shfl_xor(idx, off);
            if (ov > v || (ov == v && oi < idx)) { v = ov; idx = oi; }
        }
        // ---- masked softmax denominator at the max: sum over kept of exp(x - v)
        float s = 0.f;
        #pragma unroll
        for (int k = 0; k < 8; ++k) {
            float d = (v - x[k]) / fmaxf(fabsf(x[k]), v);
            // reference: mask = d > 2eps -> -inf. kept = !(d > 2eps); NaN => kept.
            if (!(d > TWO_EPS)) s += __expf(x[k] - v);
        }
        #pragma unroll
        for (int off = 8; off > 0; off >>= 1) s += __shfl_xor(s, off);

        val_out[pass] = 1.0f / s;
        idx_out[pass] = idx;

        // mask the selected expert for pass 1 (exp(-inf - v2) == 0 self-excludes)
        #pragma unroll
        for (int k = 0; k < 8; ++k) {
            if (e[k] == idx) x[k] = -INFINITY;
        }
    }

    if (sub == 0) {
        out[(size_t)token * 2 + 0] = (float)idx_out[0];
        out[(size_t)token * 2 + 1] = (float)idx_out[1];
        float* vals = out + (size_t)2 * T;
        vals[(size_t)token * 2 + 0] = val_out[0];
        vals[(size_t)token * 2 + 1] = val_out[1];
    }
}

extern "C" void kernel_launch(void* const* d_in, const int* in_sizes, int n_in,
                              void* d_out, int out_size, void* d_ws, size_t ws_size,
                              hipStream_t stream) {
    const float* logits = (const float*)d_in[0];
    float* out = (float*)d_out;
    const int T = in_sizes[0] / NEXPERTS;

    const int tokens_per_block = 16;  // 256 threads / 16 lanes-per-token
    const int blocks = (T + tokens_per_block - 1) / tokens_per_block;
    sparsemixer_route_kernel<<<blocks, 256, 0, stream>>>(logits, out, T);
}

// Round 4
// 41.335 us; speedup vs baseline: 1.2311x; 1.2311x over previous
//
#include <hip/hip_runtime.h>
#include <math.h>

// SparseMixer MoE routing: T tokens x 128 experts, top-2.
// Per token t:
//   (v1,i1) = max/argmax(logits)
//   kept:  (v1 - x)/max(|x|, v1) <= 2*EPS   (NaN compare-false => kept, matches jnp)
//   val0 = 1 / sum_kept exp(x - v1)
//   set x[i1] = -inf; (v2,i2) = max/argmax; same formula -> val1
// Output (floats): out[0..2T)   = indices (as float, token-major, k inner)
//                  out[2T..4T)  = values
//
// 16 lanes per token; each lane owns 8 experts via two float4 loads.
//
// R4 change vs R3 (passed, 50.9us, ~43% HBM): the mask test's 16 per-thread
// correctly-rounded f32 divides (~12 instrs each) dominate VALU. Replace with
// guarded multiply-compare: num > 0.02*den with a two-sided margin, exact
// division only within the ~2e-4 boundary window. Kept set is bit-identical.

#define NEXPERTS 128

__global__ __launch_bounds__(256) void sparsemixer_route_kernel(
    const float* __restrict__ logits,
    float* __restrict__ out,
    int T)
{
    const int gtid  = blockIdx.x * blockDim.x + threadIdx.x;
    const int token = gtid >> 4;          // 16 lanes per token
    const int sub   = threadIdx.x & 15;   // lane within the 16-group
    if (token >= T) return;

    const float4* p = reinterpret_cast<const float4*>(logits + (size_t)token * NEXPERTS);
    float4 a = p[sub];        // experts [sub*4, sub*4+4)
    float4 b = p[sub + 16];   // experts [64 + sub*4, ...)

    float x[8] = {a.x, a.y, a.z, a.w, b.x, b.y, b.z, b.w};
    int   e[8];
    #pragma unroll
    for (int k = 0; k < 4; ++k) { e[k] = sub * 4 + k; e[k + 4] = 64 + sub * 4 + k; }

    float val_out[2];
    int   idx_out[2];

    #pragma unroll
    for (int pass = 0; pass < 2; ++pass) {
        // ---- max/argmax over this lane's 8 (ascending scan => first-occurrence tie-break)
        float v = -INFINITY;
        int   idx = 0x7fffffff;
        #pragma unroll
        for (int k = 0; k < 8; ++k) {
            if (x[k] > v) { v = x[k]; idx = e[k]; }
        }
        // ---- 16-lane arg-reduce (xor masks 8,4,2,1 stay within the group)
        #pragma unroll
        for (int off = 8; off > 0; off >>= 1) {
            float ov = __shfl_xor(v, off);
            int   oi = __shfl_xor(idx, off);
            if (ov > v || (ov == v && oi < idx)) { v = ov; idx = oi; }
        }
        // ---- masked softmax denominator at the max: sum over kept of exp(x - v)
        // Reference mask: (v - x)/max(|x|, v) > 0.02 -> -inf (NaN compare-false => kept).
        // den >= 0 always, so quotient>0.02 <=> num>0.02*den, up to ~2ulp at the
        // boundary. Guard band: only run the exact divide inside it.
        // Edge cases: den==0 => num==0 => num<=lo(=0) => kept (== ref's NaN path).
        //             x==-inf => num=inf,hi=inf: inf>inf false, inf<=inf true => kept,
        //             and exp(-inf - v) == 0 contributes nothing (== ref).
        float s = 0.f;
        #pragma unroll
        for (int k = 0; k < 8; ++k) {
            float num = v - x[k];
            float den = fmaxf(fabsf(x[k]), v);
            bool masked;
            if (num > 0.02002f * den)      masked = true;
            else if (num <= 0.01998f * den) masked = false;
            else                            masked = ((num / den) > 0.02f);
            if (!masked) s += __expf(x[k] - v);
        }
        #pragma unroll
        for (int off = 8; off > 0; off >>= 1) s += __shfl_xor(s, off);

        val_out[pass] = 1.0f / s;
        idx_out[pass] = idx;

        // mask the selected expert for pass 1
        #pragma unroll
        for (int k = 0; k < 8; ++k) {
            if (e[k] == idx) x[k] = -INFINITY;
        }
    }

    if (sub == 0) {
        out[(size_t)token * 2 + 0] = (float)idx_out[0];
        out[(size_t)token * 2 + 1] = (float)idx_out[1];
        float* vals = out + (size_t)2 * T;
        vals[(size_t)token * 2 + 0] = val_out[0];
        vals[(size_t)token * 2 + 1] = val_out[1];
    }
}

extern "C" void kernel_launch(void* const* d_in, const int* in_sizes, int n_in,
                              void* d_out, int out_size, void* d_ws, size_t ws_size,
                              hipStream_t stream) {
    const float* logits = (const float*)d_in[0];
    float* out = (float*)d_out;
    const int T = in_sizes[0] / NEXPERTS;

    const int tokens_per_block = 16;  // 256 threads / 16 lanes-per-token
    const int blocks = (T + tokens_per_block - 1) / tokens_per_block;
    sparsemixer_route_kernel<<<blocks, 256, 0, stream>>>(logits, out, T);
}

// Round 5
// 39.209 us; speedup vs baseline: 1.2979x; 1.0542x over previous
//
#include <hip/hip_runtime.h>
#include <math.h>

// SparseMixer MoE routing: T tokens x 128 experts, top-2.
// R5: fused single-sweep. One joint top-2 reduction (replaces two argmax
// sweeps; 8 instead of 16 dependent shuffle rounds) + one dual-denominator
// mask/exp loop + one dual sum reduction.
//   (v1,i1,v2,i2) = top-2 with first-occurrence (smallest-index) tie-break
//     == ref's {argmax; set -inf; argmax}.
//   s1 = sum_{kept wrt v1} exp(x - v1);  val0 = 1/s1
//   s2 = sum_{kept wrt v2, excl i1} exp(x - v2);  val1 = 1/s2
//     (ref's x[i1]=-inf elem is "kept" but exp(-inf)=0 -> equivalent to excl.)
// Mask semantics: masked iff (v-x)/max(|x|,v) > 0.02, NaN-compare-false=>kept.
// Guarded multiply-compare: common path uses hi=0.02002*den branchlessly;
// elements in (0.01998, 0.02002]*den band get exact divide in a rare
// __any-guarded fixup => kept set bit-identical to the reference.
// Output (floats): out[0..2T) = indices as float; out[2T..4T) = values.
// 16 lanes/token; each lane owns 8 experts via two float4 loads.

#define NEXPERTS 128

__global__ __launch_bounds__(256) void sparsemixer_route_kernel(
    const float* __restrict__ logits,
    float* __restrict__ out,
    int T)
{
    const int gtid  = blockIdx.x * blockDim.x + threadIdx.x;
    const int token = gtid >> 4;          // 16 lanes per token
    const int sub   = threadIdx.x & 15;   // lane within the 16-group
    if (token >= T) return;

    const float4* p = reinterpret_cast<const float4*>(logits + (size_t)token * NEXPERTS);
    float4 a = p[sub];        // experts [sub*4, sub*4+4)
    float4 b = p[sub + 16];   // experts [64 + sub*4, ...)

    float x[8] = {a.x, a.y, a.z, a.w, b.x, b.y, b.z, b.w};
    int   e[8];
    #pragma unroll
    for (int k = 0; k < 4; ++k) { e[k] = sub * 4 + k; e[k + 4] = 64 + sub * 4 + k; }

    // ---- local top-2 over this lane's 8 (ascending index scan:
    //      duplicates of the max land in (m2,i2) = second occurrence, as ref)
    float m1 = x[0];        int i1 = e[0];
    float m2 = -INFINITY;   int i2 = 0x7fffffff;
    #pragma unroll
    for (int k = 1; k < 8; ++k) {
        if (x[k] > m1)      { m2 = m1; i2 = i1; m1 = x[k]; i1 = e[k]; }
        else if (x[k] > m2) { m2 = x[k]; i2 = e[k]; }
    }

    // ---- 16-lane joint top-2 butterfly (4 rounds, masks 8/4/2/1 stay in-group)
    // merge keeps {winner.top, best(winner.second, loser.top)}; loser.second
    // is provably never in the union's top-2. Ties -> smaller index.
    #pragma unroll
    for (int off = 8; off > 0; off >>= 1) {
        float om1 = __shfl_xor(m1, off); int oi1 = __shfl_xor(i1, off);
        float om2 = __shfl_xor(m2, off); int oi2 = __shfl_xor(i2, off);
        float w1, ws, lt; int wi1, wis, lti;
        if (om1 > m1 || (om1 == m1 && oi1 < i1)) {
            w1 = om1; wi1 = oi1; ws = om2; wis = oi2; lt = m1;  lti = i1;
        } else {
            w1 = m1;  wi1 = i1;  ws = m2;  wis = i2;  lt = om1; lti = oi1;
        }
        if (lt > ws || (lt == ws && lti < wis)) { m2 = lt; i2 = lti; }
        else                                    { m2 = ws; i2 = wis; }
        m1 = w1; i1 = wi1;
    }
    const float v1 = m1, v2 = m2;

    // ---- dual masked-softmax denominators (branchless common path)
    float s1 = 0.f, s2 = 0.f;
    unsigned bflags = 0;
    #pragma unroll
    for (int k = 0; k < 8; ++k) {
        const float ax = fabsf(x[k]);
        {   // side 1 (vs v1). Self term: num=0 -> kept, exp(0)=1. den=0 => ref NaN-kept, ours 0>0 false -> kept.
            float num = v1 - x[k];
            float den = fmaxf(ax, v1);
            bool  chi = num > 0.02002f * den;   // masked for sure
            bool  clo = num > 0.01998f * den;   // boundary band if clo && !chi
            float ev  = __expf(-num);           // exp(x - v1) exactly (negation exact)
            if (!chi) s1 += ev;
            if (chi != clo) bflags |= (1u << k);
        }
        {   // side 2 (vs v2), excluding expert i1 (ref: its -inf slot adds +0)
            float num = v2 - x[k];
            float den = fmaxf(ax, v2);
            bool  chi = num > 0.02002f * den;
            bool  clo = num > 0.01998f * den;
            bool  excl = (e[k] == i1);
            float ev  = __expf(-num);
            if (!chi && !excl) s2 += ev;
            if ((chi != clo) && !excl) bflags |= (1u << (k + 8));
        }
    }

    // ---- rare exact fixup (P(band) ~ 2e-5/elem): correct provisional decision
    if (__any(bflags != 0)) {
        #pragma unroll
        for (int k = 0; k < 8; ++k) {
            if (bflags & (1u << k)) {
                float num = v1 - x[k];
                float den = fmaxf(fabsf(x[k]), v1);
                bool prov = !(num > 0.02002f * den);
                bool ex   = !((num / den) > 0.02f);
                if (prov != ex) { float ev = __expf(-num); s1 += ex ? ev : -ev; }
            }
            if (bflags & (1u << (k + 8))) {
                float num = v2 - x[k];
                float den = fmaxf(fabsf(x[k]), v2);
                bool prov = !(num > 0.02002f * den);
                bool ex   = !((num / den) > 0.02f);
                if (prov != ex) { float ev = __expf(-num); s2 += ex ? ev : -ev; }
            }
        }
    }

    // ---- 16-lane dual sum butterfly
    #pragma unroll
    for (int off = 8; off > 0; off >>= 1) {
        s1 += __shfl_xor(s1, off);
        s2 += __shfl_xor(s2, off);
    }

    if (sub == 0) {
        out[(size_t)token * 2 + 0] = (float)i1;
        out[(size_t)token * 2 + 1] = (float)i2;
        float* vals = out + (size_t)2 * T;
        vals[(size_t)token * 2 + 0] = 1.0f / s1;
        vals[(size_t)token * 2 + 1] = 1.0f / s2;
    }
}

extern "C" void kernel_launch(void* const* d_in, const int* in_sizes, int n_in,
                              void* d_out, int out_size, void* d_ws, size_t ws_size,
                              hipStream_t stream) {
    const float* logits = (const float*)d_in[0];
    float* out = (float*)d_out;
    const int T = in_sizes[0] / NEXPERTS;

    const int tokens_per_block = 16;  // 256 threads / 16 lanes-per-token
    const int blocks = (T + tokens_per_block - 1) / tokens_per_block;
    sparsemixer_route_kernel<<<blocks, 256, 0, stream>>>(logits, out, T);
}

// Round 6
// 35.438 us; speedup vs baseline: 1.4360x; 1.1064x over previous
//
#include <hip/hip_runtime.h>
#include <math.h>

// SparseMixer MoE routing: T tokens x 128 experts, top-2.
// R6: serial one-token-per-lane. 64 tokens/wave, zero cross-lane ops.
//   - whole 512B row in registers via 32x global_load_dwordx4 (imm offsets)
//   - top-2 scan with first-occurrence tie-break == ref's {argmax; -inf; argmax}
//   - one exp per element: ev=exp(x-v1) feeds s1 and t2; s2 = t2*exp(v1-v2)
//     (rescale exact to ~2e-7 rel; ref's -inf slot self-excludes -> k!=i1 here)
//   - mask: masked iff (v-x)/max(|x|,v) > 0.02 (NaN-compare-false => kept).
//     Implemented as num > 0.02f*den (den>=0): disagreement band vs the
//     reference's divide is ~1e-9 relative (~1e-4 expected flips per full
//     262144x128x2 test) — negligible vs absmax threshold.
//     Edge: den==0 => num==0 => 0>0 false => kept (== ref NaN path).
// Output (floats): out[0..2T) = indices as float; out[2T..4T) = values.

#define NEXPERTS 128

__global__ __launch_bounds__(256, 3) void sparsemixer_route_kernel(
    const float* __restrict__ logits,
    float* __restrict__ out,
    int T)
{
    const int token = blockIdx.x * blockDim.x + threadIdx.x;
    if (token >= T) return;

    const float4* p = reinterpret_cast<const float4*>(logits + (size_t)token * NEXPERTS);

    float x[NEXPERTS];
    #pragma unroll
    for (int c = 0; c < NEXPERTS / 4; ++c) {
        float4 v4 = p[c];
        x[c * 4 + 0] = v4.x; x[c * 4 + 1] = v4.y;
        x[c * 4 + 2] = v4.z; x[c * 4 + 3] = v4.w;
    }

    // ---- top-2 scan, first-occurrence tie-break (matches ref duplicate-max
    //      semantics: [5,5,3]->i1=0,i2=1; [3,5,5]->i1=1,i2=2; [5,4,4]->i2=1)
    float m1 = x[0];      int i1 = 0;
    float m2 = -INFINITY; int i2 = 0x7fffffff;
    #pragma unroll
    for (int k = 1; k < NEXPERTS; ++k) {
        if (x[k] > m1)      { m2 = m1; i2 = i1; m1 = x[k]; i1 = k; }
        else if (x[k] > m2) { m2 = x[k]; i2 = k; }
    }
    const float v1 = m1, v2 = m2;

    // ---- dual masked-softmax denominators, one exp per element
    float s1 = 0.f, t2 = 0.f;
    #pragma unroll
    for (int k = 0; k < NEXPERTS; ++k) {
        float ax   = fabsf(x[k]);
        float num1 = v1 - x[k];
        float num2 = v2 - x[k];
        float den1 = fmaxf(ax, v1);
        float den2 = fmaxf(ax, v2);
        bool kept1 = !(num1 > 0.02f * den1);
        bool kept2 = !(num2 > 0.02f * den2) && (k != i1);
        float ev = __expf(-num1);          // exp(x[k] - v1), negation exact
        if (kept1) s1 += ev;
        if (kept2) t2 += ev;
    }
    // s2 = sum_{kept2} exp(x - v2) = e^{v1-v2} * sum_{kept2} exp(x - v1)
    float s2 = t2 * __expf(v1 - v2);

    out[(size_t)token * 2 + 0] = (float)i1;
    out[(size_t)token * 2 + 1] = (float)i2;
    float* vals = out + (size_t)2 * T;
    vals[(size_t)token * 2 + 0] = 1.0f / s1;
    vals[(size_t)token * 2 + 1] = 1.0f / s2;
}

extern "C" void kernel_launch(void* const* d_in, const int* in_sizes, int n_in,
                              void* d_out, int out_size, void* d_ws, size_t ws_size,
                              hipStream_t stream) {
    const float* logits = (const float*)d_in[0];
    float* out = (float*)d_out;
    const int T = in_sizes[0] / NEXPERTS;

    const int blocks = (T + 255) / 256;   // one token per thread
    sparsemixer_route_kernel<<<blocks, 256, 0, stream>>>(logits, out, T);
}

// Round 7
// 32.388 us; speedup vs baseline: 1.5712x; 1.0942x over previous
//
#include <hip/hip_runtime.h>
#include <math.h>

// SparseMixer MoE routing: T tokens x 128 experts, top-2.
// R7: 4 lanes/token, 2 tokens/thread, all global loads issued up front so
// token-1 loads stay in flight during token-0 compute (explicit mem/VALU
// overlap — R5/R6 timings were additive VALU+HBM, i.e. no overlap).
// Semantics (all passed absmax 0.0 in R5/R6):
//   top-2 with first-occurrence tie-break == ref {argmax; -inf; argmax}
//   masked iff (v-x) > 0.02*max(|x|,v)   (NaN path: den=0 => kept, == ref)
//   s1 = sum_{kept1} exp(x-v1); s2 = exp(v1-v2) * sum_{kept2, k!=i1} exp(x-v1)
// Output (floats): out[0..2T) = indices as float; out[2T..4T) = values.

#define NEXPERTS 128
#define CHUNKS 8   // 8 float4 chunks per lane = 32 elements; 4 lanes -> 128

__device__ __forceinline__ void process_token(
    const float4* X, int sub, int token, float* out, int T)
{
    // ---- local top-2 over this lane's 32 elements.
    // Track LOCAL code L = 16*c + j (global e = 4*sub + L); ascending (c,j)
    // scan == ascending e => first-occurrence tie-break within lane.
    float m1 = -INFINITY, m2 = -INFINITY;
    int   l1 = 0x7fffff, l2 = 0x7fffff;
    #pragma unroll
    for (int c = 0; c < CHUNKS; ++c) {
        const float xs[4] = {X[c].x, X[c].y, X[c].z, X[c].w};
        #pragma unroll
        for (int j = 0; j < 4; ++j) {
            const float xv = xs[j];
            const int   L  = 16 * c + j;
            if (xv > m1)      { m2 = m1; l2 = l1; m1 = xv; l1 = L; }
            else if (xv > m2) { m2 = xv; l2 = L; }
        }
    }
    int i1 = 4 * sub + l1;   // global expert indices
    int i2 = 4 * sub + l2;

    // ---- 4-lane joint top-2 butterfly (offsets 2,1 stay in the group).
    // Merge keeps {winner.top, best(winner.second, loser.top)}; ties -> smaller idx.
    #pragma unroll
    for (int off = 2; off > 0; off >>= 1) {
        float om1 = __shfl_xor(m1, off); int oi1 = __shfl_xor(i1, off);
        float om2 = __shfl_xor(m2, off); int oi2 = __shfl_xor(i2, off);
        float w1, ws, lt; int wi1, wis, lti;
        if (om1 > m1 || (om1 == m1 && oi1 < i1)) {
            w1 = om1; wi1 = oi1; ws = om2; wis = oi2; lt = m1;  lti = i1;
        } else {
            w1 = m1;  wi1 = i1;  ws = m2;  wis = i2;  lt = om1; lti = oi1;
        }
        if (lt > ws || (lt == ws && lti < wis)) { m2 = lt; i2 = lti; }
        else                                    { m2 = ws; i2 = wis; }
        m1 = w1; i1 = wi1;
    }
    const float v1 = m1, v2 = m2;
    const int   d  = i1 - 4 * sub;   // excl element: local code L == d

    // ---- dual masked-softmax partial sums, one exp per element
    float s1 = 0.f, t2 = 0.f;
    #pragma unroll
    for (int c = 0; c < CHUNKS; ++c) {
        const float xs[4] = {X[c].x, X[c].y, X[c].z, X[c].w};
        #pragma unroll
        for (int j = 0; j < 4; ++j) {
            const float xv  = xs[j];
            const int   L   = 16 * c + j;
            const float ax  = fabsf(xv);
            const float num1 = v1 - xv;
            const float num2 = v2 - xv;
            const bool kept1 = !(num1 > 0.02f * fmaxf(ax, v1));
            const bool kept2 = !(num2 > 0.02f * fmaxf(ax, v2));
            const float ev = __expf(-num1);          // exp(xv - v1)
            if (kept1) s1 += ev;
            float t = kept2 ? ev : 0.f;
            if (L == d) t = 0.f;                     // exclude expert i1
            t2 += t;
        }
    }
    // ---- 4-lane sum butterfly
    #pragma unroll
    for (int off = 2; off > 0; off >>= 1) {
        s1 += __shfl_xor(s1, off);
        t2 += __shfl_xor(t2, off);
    }

    if (sub == 0) {
        const float s2 = t2 * __expf(v1 - v2);
        out[(size_t)token * 2 + 0] = (float)i1;
        out[(size_t)token * 2 + 1] = (float)i2;
        float* vals = out + (size_t)2 * T;
        vals[(size_t)token * 2 + 0] = 1.0f / s1;
        vals[(size_t)token * 2 + 1] = 1.0f / s2;
    }
}

__global__ __launch_bounds__(256, 4) void sparsemixer_route_kernel(
    const float* __restrict__ logits,
    float* __restrict__ out,
    int T)
{
    const int tid = blockIdx.x * blockDim.x + threadIdx.x;
    const int grp = tid >> 2;                                // token-group id
    const int sub = threadIdx.x & 3;                         // lane in group
    const int G   = (gridDim.x * blockDim.x) >> 2;           // groups per grid
    const int t0  = grp;
    const int t1  = grp + G;

    // Issue ALL loads up front: t1's 8 dwordx4 remain outstanding through
    // t0's compute (compiler waits at vmcnt(8)), keeping HBM busy.
    float4 X0[CHUNKS], X1[CHUNKS];
    if (t0 < T) {
        const float4* p0 = reinterpret_cast<const float4*>(logits + (size_t)t0 * NEXPERTS);
        #pragma unroll
        for (int c = 0; c < CHUNKS; ++c) X0[c] = p0[sub + c * 4];
    }
    if (t1 < T) {
        const float4* p1 = reinterpret_cast<const float4*>(logits + (size_t)t1 * NEXPERTS);
        #pragma unroll
        for (int c = 0; c < CHUNKS; ++c) X1[c] = p1[sub + c * 4];
    }

    if (t0 < T) process_token(X0, sub, t0, out, T);
    if (t1 < T) process_token(X1, sub, t1, out, T);
}

extern "C" void kernel_launch(void* const* d_in, const int* in_sizes, int n_in,
                              void* d_out, int out_size, void* d_ws, size_t ws_size,
                              hipStream_t stream) {
    const float* logits = (const float*)d_in[0];
    float* out = (float*)d_out;
    const int T = in_sizes[0] / NEXPERTS;

    // 64 groups/block, 2 tokens/group -> 128 tokens per block
    const int blocks = (T + 127) / 128;
    sparsemixer_route_kernel<<<blocks, 256, 0, stream>>>(logits, out, T);
}